// Round 12
// baseline (594.178 us; speedup 1.0000x reference)
//
#include <hip/hip_runtime.h>
#include <hip/hip_bf16.h>

typedef __attribute__((ext_vector_type(8))) short short8;
typedef __attribute__((ext_vector_type(4))) float f32x4;
typedef __attribute__((address_space(1))) const void gvoid_t;
typedef __attribute__((address_space(3))) void lvoid_t;

#define NB 4096   // B
#define DD 256    // D
#define TWOB 8192
#define NTILES 2080u   // 64*65/2 symmetric 128x128 tiles
#define GSUM_BLOCKS 16

__device__ __forceinline__ unsigned short f2bf(float f) {
  unsigned int u = __float_as_uint(f);
  u += 0x7fffu + ((u >> 16) & 1u);
  return (unsigned short)(u >> 16);
}
__device__ __forceinline__ float bf2f(unsigned short s) {
  return __uint_as_float(((unsigned int)s) << 16);
}

// ws layout (bytes), NOTHING needs pre-zeroing (every read slot is written):
//   [65536, 4259840)   znb: 8192x256 bf16
//   [4259840, +64KB)   vsum_part[16][4][256] f32
//   [4325376, +256)    cnt_part[16][4] int
//   [4325632, +4KB)    ppos[1024] f32 (per-norm-block pos partials)
//   [4329728, +2MB)    rpart[64][64][128] f32 (row sums of exp tiles, tc>=tr)
//   [6426880, +2MB)    cpart[64][64][128] f32 (col sums, tc>tr)
//
// R11 post-mortem: per-block latency matches R1 (~12us) but achieved
// residency is 1.9 blocks/CU vs R1's 2.9 (same resources). Suspect: the
// epilogue's contended den atomics (512/block, incl. 16-lane same-line
// bursts) delay slot recycling after retire. R12 removes EVERY atomic in
// the pipeline: tiles/norm write private partials (plain stores), tail
// reconstructs. Also fixes R10/R11's zero-vs-atomicAdd race on scal[0].

// ---------------- kernel A: normalize -> znb bf16; ppos[b] ----------------
__global__ __launch_bounds__(256) void norm_kernel(const float* __restrict__ zi,
                                                   const float* __restrict__ zj,
                                                   float* __restrict__ ppos,
                                                   unsigned short* __restrict__ znb) {
  __shared__ float sred[4];
  const int lane = threadIdx.x & 63, wave = threadIdx.x >> 6;
  const int i = blockIdx.x * 4 + wave;

  float4 a = ((const float4*)(zi + (size_t)i * DD))[lane];
  float4 b = ((const float4*)(zj + (size_t)i * DD))[lane];
  float sa = a.x * a.x + a.y * a.y + a.z * a.z + a.w * a.w;
  float sb = b.x * b.x + b.y * b.y + b.z * b.z + b.w * b.w;
  float sab = a.x * b.x + a.y * b.y + a.z * b.z + a.w * b.w;
#pragma unroll
  for (int m = 32; m >= 1; m >>= 1) {
    sa += __shfl_xor(sa, m);
    sb += __shfl_xor(sb, m);
    sab += __shfl_xor(sab, m);
  }
  float ra = 1.0f / fmaxf(sqrtf(sa), 1e-8f);
  float rb = 1.0f / fmaxf(sqrtf(sb), 1e-8f);
  ushort4 oa, ob;
  oa.x = f2bf(a.x * ra); oa.y = f2bf(a.y * ra); oa.z = f2bf(a.z * ra); oa.w = f2bf(a.w * ra);
  ob.x = f2bf(b.x * rb); ob.y = f2bf(b.y * rb); ob.z = f2bf(b.z * rb); ob.w = f2bf(b.w * rb);
  ((ushort4*)(znb + (size_t)i * DD))[lane] = oa;
  ((ushort4*)(znb + (size_t)(i + NB) * DD))[lane] = ob;

  if (lane == 0) sred[wave] = sab * ra * rb;  // exact fp32 pos (row i)
  __syncthreads();
  if (threadIdx.x == 0)
    ppos[blockIdx.x] = sred[0] + sred[1] + sred[2] + sred[3];  // plain store
}

// ---------------- kernel B: gsum blocks + den tiles; ZERO atomics ---------
__global__ __launch_bounds__(256, 3) void den_kernel(const int* __restrict__ sf,
                                                     const unsigned short* __restrict__ znb,
                                                     float* __restrict__ vsum_part,
                                                     int* __restrict__ cnt_part,
                                                     float* __restrict__ rpart,
                                                     float* __restrict__ cpart) {
  __shared__ __align__(16) unsigned short As[2][4096];  // 2 x 8KB = 32768 LDS
  __shared__ __align__(16) unsigned short Bs[2][4096];

  const int tid = threadIdx.x;
  const int lane = tid & 63, wave = tid >> 6;

  if (blockIdx.x < GSUM_BLOCKS) {
    // ---- gsum: 256 rows, LDS reduce, plain stores to private partials ----
    const int b = blockIdx.x;
    const int r0 = b * 256;
    float acc[4][4];
#pragma unroll
    for (int q = 0; q < 4; ++q)
#pragma unroll
      for (int e = 0; e < 4; ++e) acc[q][e] = 0.f;
    int cnt[4] = {0, 0, 0, 0};
    const int rw = r0 + wave * 64;
    for (int k = 0; k < 64; ++k) {
      int row = rw + k;
      int g = sf[row];
      ushort4 v = ((const ushort4*)(znb + (size_t)row * DD))[lane];
      float f0 = bf2f(v.x), f1 = bf2f(v.y), f2 = bf2f(v.z), f3 = bf2f(v.w);
#pragma unroll
      for (int q = 0; q < 4; ++q) {
        bool sel = (g == q);
        acc[q][0] += sel ? f0 : 0.f;
        acc[q][1] += sel ? f1 : 0.f;
        acc[q][2] += sel ? f2 : 0.f;
        acc[q][3] += sel ? f3 : 0.f;
        cnt[q] += sel ? 1 : 0;
      }
    }
    float4* lsd = (float4*)&As[0][0];
    int* lcnt = (int*)&Bs[0][0];
#pragma unroll
    for (int q = 0; q < 4; ++q) {
      float4 t;
      t.x = acc[q][0]; t.y = acc[q][1]; t.z = acc[q][2]; t.w = acc[q][3];
      lsd[(wave * 4 + q) * 64 + lane] = t;
    }
    if (lane == 0) {
#pragma unroll
      for (int q = 0; q < 4; ++q) lcnt[wave * 4 + q] = cnt[q];
    }
    __syncthreads();
    {
      int g = tid >> 6, l = tid & 63;
      float4 s0 = lsd[(0 + g) * 64 + l];
      float4 s1 = lsd[(4 + g) * 64 + l];
      float4 s2 = lsd[(8 + g) * 64 + l];
      float4 s3 = lsd[(12 + g) * 64 + l];
      float4 s;
      s.x = s0.x + s1.x + s2.x + s3.x;
      s.y = s0.y + s1.y + s2.y + s3.y;
      s.z = s0.z + s1.z + s2.z + s3.z;
      s.w = s0.w + s1.w + s2.w + s3.w;
      ((float4*)(vsum_part + (size_t)(b * 4 + g) * 256))[l] = s;
      if (tid < 4)
        cnt_part[b * 4 + tid] = lcnt[tid] + lcnt[4 + tid] + lcnt[8 + tid] + lcnt[12 + tid];
    }
    return;
  }

  // ---- one symmetric den tile ------------------------------------------
  unsigned t = blockIdx.x - GSUM_BLOCKS;
  unsigned tr = 0;
  while (t >= 64u - tr) { t -= 64u - tr; ++tr; }
  unsigned tc = tr + t;
  const bool diag = (tr == tc);
  const size_t rowbase = (size_t)tr * 128, colbase = (size_t)tc * 128;

  const int u = lane >> 3;
  const int cp = (lane & 7) ^ u;
  const int ri = 2 * u + (cp >> 2);
  const int kelem = (cp & 3) * 8;
  const int slot = ((((lane & 1) << 2) | (lane >> 4)) ^ ((lane >> 1) & 7));
  const int fragoff = ((lane & 15) >> 1) * 128 + slot * 16;
  const int wrow = wave & 1, wcol = wave >> 1;

  f32x4 zero = {0.f, 0.f, 0.f, 0.f};
  f32x4 acc[4][4];
#pragma unroll
  for (int i = 0; i < 4; ++i)
#pragma unroll
    for (int j = 0; j < 4; ++j) acc[i][j] = zero;

  auto stage = [&](int kt, int buf) {
#pragma unroll
    for (int j = 0; j < 2; ++j) {
      int is = wave * 2 + j;
      const unsigned short* gpa = znb + (rowbase + is * 16 + ri) * DD + kt * 32 + kelem;
      __builtin_amdgcn_global_load_lds((gvoid_t*)gpa, (lvoid_t*)&As[buf][is * 512], 16, 0, 0);
      const unsigned short* gpb = znb + (colbase + is * 16 + ri) * DD + kt * 32 + kelem;
      __builtin_amdgcn_global_load_lds((gvoid_t*)gpb, (lvoid_t*)&Bs[buf][is * 512], 16, 0, 0);
    }
  };

  stage(0, 0);
  __syncthreads();
#pragma unroll
  for (int kt = 0; kt < 8; ++kt) {
    if (kt < 7) stage(kt + 1, (kt + 1) & 1);
    const int buf = kt & 1;
    short8 af[4], bfr[4];
#pragma unroll
    for (int mi = 0; mi < 4; ++mi)
      af[mi] = *(const short8*)((const char*)&As[buf][0] + wrow * 4096 + mi * 1024 + fragoff);
#pragma unroll
    for (int ni = 0; ni < 4; ++ni)
      bfr[ni] = *(const short8*)((const char*)&Bs[buf][0] + wcol * 4096 + ni * 1024 + fragoff);
#pragma unroll
    for (int mi = 0; mi < 4; ++mi)
#pragma unroll
      for (int ni = 0; ni < 4; ++ni)
        acc[mi][ni] = __builtin_amdgcn_mfma_f32_16x16x32_bf16(af[mi], bfr[ni], acc[mi][ni], 0, 0, 0);
    __syncthreads();
  }

  // epilogue: e = exp(2S); wave-reduce row/col sums; block-combine via LDS
  // (aliased on As, dead after last kt barrier); PLAIN stores to private
  // rpart/cpart slots. C layout: col=lane&15, row=(lane>>4)*4+reg.
  float rsum[4][4];
  float csum[4] = {0.f, 0.f, 0.f, 0.f};
#pragma unroll
  for (int mi = 0; mi < 4; ++mi)
#pragma unroll
    for (int r = 0; r < 4; ++r) rsum[mi][r] = 0.f;
#pragma unroll
  for (int mi = 0; mi < 4; ++mi)
#pragma unroll
    for (int ni = 0; ni < 4; ++ni)
#pragma unroll
      for (int r = 0; r < 4; ++r) {
        float e = __expf(2.0f * acc[mi][ni][r]);
        rsum[mi][r] += e;
        csum[ni] += e;
      }
#pragma unroll
  for (int m = 1; m < 16; m <<= 1)
#pragma unroll
    for (int mi = 0; mi < 4; ++mi)
#pragma unroll
      for (int r = 0; r < 4; ++r) rsum[mi][r] += __shfl_xor(rsum[mi][r], m);
#pragma unroll
  for (int m = 16; m < 64; m <<= 1)
#pragma unroll
    for (int ni = 0; ni < 4; ++ni) csum[ni] += __shfl_xor(csum[ni], m);

  float* Lr = (float*)&As[0][0];  // [2][128] by wcol
  float* Lc = Lr + 256;           // [2][128] by wrow
  if ((lane & 15) == 0) {
    int h = lane >> 4;
#pragma unroll
    for (int mi = 0; mi < 4; ++mi)
#pragma unroll
      for (int r = 0; r < 4; ++r)
        Lr[wcol * 128 + wrow * 64 + mi * 16 + h * 4 + r] = rsum[mi][r];
  }
  if (lane < 16) {
#pragma unroll
    for (int ni = 0; ni < 4; ++ni)
      Lc[wrow * 128 + wcol * 64 + ni * 16 + lane] = csum[ni];
  }
  __syncthreads();
  if (tid < 128) {
    size_t tbase = ((size_t)(tr << 6) + tc) * 128;
    rpart[tbase + tid] = Lr[tid] + Lr[128 + tid];
    if (!diag) cpart[tbase + tid] = Lc[tid] + Lc[128 + tid];
  }
}

// ---------------- kernel C: tail (1 block, atomic-free) -------------------
__global__ __launch_bounds__(256) void tail_kernel(const float* __restrict__ rpart,
                                                   const float* __restrict__ cpart,
                                                   const float* __restrict__ vsum_part,
                                                   const int* __restrict__ cnt_part,
                                                   const float* __restrict__ ppos,
                                                   float* __restrict__ out) {
  __shared__ float sred[32];
  const int tid = threadIdx.x;
  const int lane = tid & 63, wave = tid >> 6;

  const float e2 = __expf(2.0f);
  float ls = 0.f;
  for (int it = 0; it < 32; ++it) {
    int r = it * 256 + tid;
    int tr = r >> 7, l = r & 127;
    float d = 0.f;
    for (int tc = tr; tc < 64; ++tc) d += rpart[((size_t)(tr << 6) + tc) * 128 + l];
    for (int t = 0; t < tr; ++t) d += cpart[((size_t)(t << 6) + tr) * 128 + l];
    ls += __logf(d - e2);
  }
#pragma unroll
  for (int m = 32; m >= 1; m >>= 1) ls += __shfl_xor(ls, m);
  if (lane == 0) sred[wave] = ls;

  float pp = 0.f;
#pragma unroll
  for (int k = 0; k < 4; ++k) pp += ppos[k * 256 + tid];
#pragma unroll
  for (int m = 32; m >= 1; m >>= 1) pp += __shfl_xor(pp, m);
  if (lane == 0) sred[8 + wave] = pp;

  float gp[4];
#pragma unroll
  for (int g = 0; g < 4; ++g) {
    float v = 0.f;
#pragma unroll
    for (int b = 0; b < 16; ++b) v += vsum_part[(size_t)(b * 4 + g) * 256 + tid];
    gp[g] = v * v;
#pragma unroll
    for (int m = 32; m >= 1; m >>= 1) gp[g] += __shfl_xor(gp[g], m);
  }
  if (lane == 0) {
#pragma unroll
    for (int g = 0; g < 4; ++g) sred[12 + wave * 4 + g] = gp[g];
  }
  __syncthreads();
  if (tid == 0) {
    float lsum = sred[0] + sred[1] + sred[2] + sred[3];
    float psum = sred[8] + sred[9] + sred[10] + sred[11];
    float contrastive = (lsum - 4.0f * psum) / (float)TWOB;
    float fsum = 0.f;
    int uniq = 0;
#pragma unroll
    for (int q = 0; q < 4; ++q) {
      int ci = 0;
#pragma unroll
      for (int b = 0; b < 16; ++b) ci += cnt_part[b * 4 + q];
      float gsq = sred[12 + q] + sred[16 + q] + sred[20 + q] + sred[24 + q];
      float c = (float)ci;
      if (ci > 0) uniq++;
      if (ci > 1) fsum += gsq / (c * (c - 1.0f));
    }
    out[0] = contrastive + 0.1f * (fsum / (uniq > 0 ? (float)uniq : 1.0f));
  }
}

extern "C" void kernel_launch(void* const* d_in, const int* in_sizes, int n_in,
                              void* d_out, int out_size, void* d_ws, size_t ws_size,
                              hipStream_t stream) {
  const float* zi = (const float*)d_in[0];
  const float* zj = (const float*)d_in[1];
  const int* sf = (const int*)d_in[2];
  float* out = (float*)d_out;
  char* ws = (char*)d_ws;
  unsigned short* znb = (unsigned short*)(ws + 65536);   // 8192x256 bf16 (4MB)
  float* vsum_part = (float*)(ws + 4259840);             // 16x4x256 f32
  int* cnt_part = (int*)(ws + 4325376);                  // 16x4 int
  float* ppos = (float*)(ws + 4325632);                  // 1024 f32
  float* rpart = (float*)(ws + 4329728);                 // 64x64x128 f32 (2MB)
  float* cpart = (float*)(ws + 6426880);                 // 64x64x128 f32 (2MB)

  hipLaunchKernelGGL(norm_kernel, dim3(1024), dim3(256), 0, stream, zi, zj, ppos, znb);
  hipLaunchKernelGGL(den_kernel, dim3(NTILES + GSUM_BLOCKS), dim3(256), 0, stream,
                     sf, znb, vsum_part, cnt_part, rpart, cpart);
  hipLaunchKernelGGL(tail_kernel, dim3(1), dim3(256), 0, stream,
                     rpart, cpart, vsum_part, cnt_part, ppos, out);
}

// Round 14
// 138.901 us; speedup vs baseline: 4.2777x; 4.2777x over previous
//
#include <hip/hip_runtime.h>
#include <hip/hip_bf16.h>

typedef __attribute__((ext_vector_type(8))) short short8;
typedef __attribute__((ext_vector_type(4))) float f32x4;
typedef __attribute__((address_space(1))) const void gvoid_t;
typedef __attribute__((address_space(3))) void lvoid_t;

#define NB 4096   // B
#define DD 256    // D
#define TWOB 8192
#define NTILES 2080u   // 64*65/2 symmetric 128x128 tiles
#define GSUM_BLOCKS 16
#define GRID_B (NTILES + GSUM_BLOCKS)   // 2096 = 48*33 + 16*32

__device__ __forceinline__ unsigned short f2bf(float f) {
  unsigned int u = __float_as_uint(f);
  u += 0x7fffu + ((u >> 16) & 1u);
  return (unsigned short)(u >> 16);
}
__device__ __forceinline__ float bf2f(unsigned short s) {
  return __uint_as_float(((unsigned int)s) << 16);
}
__device__ __forceinline__ void astf(float* p, float v) {
  __hip_atomic_store(p, v, __ATOMIC_RELAXED, __HIP_MEMORY_SCOPE_AGENT);
}

// ws layout (floats from base, zeroed region = wsf[0..10495] by norm blks 0..40):
//   wsf[0..8191]          den
//   wsf+8192              leaves[64] u32, stride 32 (128B lines)
//   wsf+10240             root u32
// bytes:
//   [65536, 4259840)      znb 8192x256 bf16
//   [4259840, 4276224)    vsum_part[16][4][256] f32 (relaxed agent stores)
//   [4276224, 4276480)    cnt_part[16][4] int (relaxed agent stores)
//   [4276480, 4280576)    ppos[1024] f32 (plain stores, kernel-A boundary)
//
// R13 post-mortem: distributed per-row reduction never finalized (out=0);
// unfindable blind. R14 = composition of ONLY proven pieces: R11 tiles
// (atomic den), R11 atomic-free gsum (relaxed stores for same-kernel
// visibility), R12 norm/ppos, R8 hierarchical arrive VERBATIM (proven
// correct at grid 2096), R8/R12 last-block tail. 2 dispatches.

// ---------------- kernel A: zero accum region; normalize; ppos ------------
__global__ __launch_bounds__(256) void norm_kernel(const float* __restrict__ zi,
                                                   const float* __restrict__ zj,
                                                   float* __restrict__ wsf,
                                                   float* __restrict__ ppos,
                                                   unsigned short* __restrict__ znb) {
  __shared__ float sred[4];
  if (blockIdx.x < 41) wsf[blockIdx.x * 256 + threadIdx.x] = 0.f;
  const int lane = threadIdx.x & 63, wave = threadIdx.x >> 6;
  const int i = blockIdx.x * 4 + wave;

  float4 a = ((const float4*)(zi + (size_t)i * DD))[lane];
  float4 b = ((const float4*)(zj + (size_t)i * DD))[lane];
  float sa = a.x * a.x + a.y * a.y + a.z * a.z + a.w * a.w;
  float sb = b.x * b.x + b.y * b.y + b.z * b.z + b.w * b.w;
  float sab = a.x * b.x + a.y * b.y + a.z * b.z + a.w * b.w;
#pragma unroll
  for (int m = 32; m >= 1; m >>= 1) {
    sa += __shfl_xor(sa, m);
    sb += __shfl_xor(sb, m);
    sab += __shfl_xor(sab, m);
  }
  float ra = 1.0f / fmaxf(sqrtf(sa), 1e-8f);
  float rb = 1.0f / fmaxf(sqrtf(sb), 1e-8f);
  ushort4 oa, ob;
  oa.x = f2bf(a.x * ra); oa.y = f2bf(a.y * ra); oa.z = f2bf(a.z * ra); oa.w = f2bf(a.w * ra);
  ob.x = f2bf(b.x * rb); ob.y = f2bf(b.y * rb); ob.z = f2bf(b.z * rb); ob.w = f2bf(b.w * rb);
  ((ushort4*)(znb + (size_t)i * DD))[lane] = oa;
  ((ushort4*)(znb + (size_t)(i + NB) * DD))[lane] = ob;

  if (lane == 0) sred[wave] = sab * ra * rb;  // exact fp32 pos (row i)
  __syncthreads();
  if (threadIdx.x == 0)
    ppos[blockIdx.x] = sred[0] + sred[1] + sred[2] + sred[3];
}

// ---------------- kernel B: gsum + tiles + R8 arrive + tail ---------------
__global__ __launch_bounds__(256, 3) void den_kernel(const int* __restrict__ sf,
                                                     float* __restrict__ wsf,
                                                     const unsigned short* __restrict__ znb,
                                                     float* __restrict__ vsum_part,
                                                     int* __restrict__ cnt_part,
                                                     const float* __restrict__ ppos,
                                                     float* __restrict__ out) {
  __shared__ __align__(16) unsigned short As[2][4096];  // 2 x 8KB = 32768 LDS
  __shared__ __align__(16) unsigned short Bs[2][4096];
  float* sred = (float*)&As[0][0];     // tail scratch (aliased, dead by then)
  int* shp = (int*)&Bs[0][0];          // sh_last

  float* den = wsf;
  unsigned* leaves = (unsigned*)(wsf + 8192);  // 64 counters, stride 32
  unsigned* root = (unsigned*)(wsf + 10240);

  const int tid = threadIdx.x;
  const int lane = tid & 63, wave = tid >> 6;

  if (blockIdx.x < GSUM_BLOCKS) {
    // ---- gsum: 256 rows, LDS reduce, relaxed agent stores (R11 logic) ----
    const int b = blockIdx.x;
    const int r0 = b * 256;
    float acc[4][4];
#pragma unroll
    for (int q = 0; q < 4; ++q)
#pragma unroll
      for (int e = 0; e < 4; ++e) acc[q][e] = 0.f;
    int cnt[4] = {0, 0, 0, 0};
    const int rw = r0 + wave * 64;
    for (int k = 0; k < 64; ++k) {
      int row = rw + k;
      int g = sf[row];
      ushort4 v = ((const ushort4*)(znb + (size_t)row * DD))[lane];
      float f0 = bf2f(v.x), f1 = bf2f(v.y), f2 = bf2f(v.z), f3 = bf2f(v.w);
#pragma unroll
      for (int q = 0; q < 4; ++q) {
        bool sel = (g == q);
        acc[q][0] += sel ? f0 : 0.f;
        acc[q][1] += sel ? f1 : 0.f;
        acc[q][2] += sel ? f2 : 0.f;
        acc[q][3] += sel ? f3 : 0.f;
        cnt[q] += sel ? 1 : 0;
      }
    }
    float4* lsd = (float4*)&As[0][0];
    int* lcnt = (int*)&Bs[0][0];
#pragma unroll
    for (int q = 0; q < 4; ++q) {
      float4 t;
      t.x = acc[q][0]; t.y = acc[q][1]; t.z = acc[q][2]; t.w = acc[q][3];
      lsd[(wave * 4 + q) * 64 + lane] = t;
    }
    if (lane == 0) {
#pragma unroll
      for (int q = 0; q < 4; ++q) lcnt[wave * 4 + q] = cnt[q];
    }
    __syncthreads();
    {
      int g = tid >> 6, l = tid & 63;
      float4 s0 = lsd[(0 + g) * 64 + l];
      float4 s1 = lsd[(4 + g) * 64 + l];
      float4 s2 = lsd[(8 + g) * 64 + l];
      float4 s3 = lsd[(12 + g) * 64 + l];
      size_t base = (size_t)(b * 4 + g) * 256 + l * 4;
      astf(&vsum_part[base + 0], s0.x + s1.x + s2.x + s3.x);
      astf(&vsum_part[base + 1], s0.y + s1.y + s2.y + s3.y);
      astf(&vsum_part[base + 2], s0.z + s1.z + s2.z + s3.z);
      astf(&vsum_part[base + 3], s0.w + s1.w + s2.w + s3.w);
      if (tid < 4) {
        int c = lcnt[tid] + lcnt[4 + tid] + lcnt[8 + tid] + lcnt[12 + tid];
        __hip_atomic_store(&cnt_part[b * 4 + tid], c, __ATOMIC_RELAXED, __HIP_MEMORY_SCOPE_AGENT);
      }
    }
  } else {
    // ---- one symmetric den tile (R11 verbatim) --------------------------
    unsigned t = blockIdx.x - GSUM_BLOCKS;
    unsigned tr = 0;
    while (t >= 64u - tr) { t -= 64u - tr; ++tr; }
    unsigned tc = tr + t;
    const bool diag = (tr == tc);
    const size_t rowbase = (size_t)tr * 128, colbase = (size_t)tc * 128;

    const int u = lane >> 3;
    const int cp = (lane & 7) ^ u;
    const int ri = 2 * u + (cp >> 2);
    const int kelem = (cp & 3) * 8;
    const int slot = ((((lane & 1) << 2) | (lane >> 4)) ^ ((lane >> 1) & 7));
    const int fragoff = ((lane & 15) >> 1) * 128 + slot * 16;
    const int wrow = wave & 1, wcol = wave >> 1;

    f32x4 zero = {0.f, 0.f, 0.f, 0.f};
    f32x4 acc[4][4];
#pragma unroll
    for (int i = 0; i < 4; ++i)
#pragma unroll
      for (int j = 0; j < 4; ++j) acc[i][j] = zero;

    auto stage = [&](int kt, int buf) {
#pragma unroll
      for (int j = 0; j < 2; ++j) {
        int is = wave * 2 + j;
        const unsigned short* gpa = znb + (rowbase + is * 16 + ri) * DD + kt * 32 + kelem;
        __builtin_amdgcn_global_load_lds((gvoid_t*)gpa, (lvoid_t*)&As[buf][is * 512], 16, 0, 0);
        const unsigned short* gpb = znb + (colbase + is * 16 + ri) * DD + kt * 32 + kelem;
        __builtin_amdgcn_global_load_lds((gvoid_t*)gpb, (lvoid_t*)&Bs[buf][is * 512], 16, 0, 0);
      }
    };

    stage(0, 0);
    __syncthreads();
#pragma unroll
    for (int kt = 0; kt < 8; ++kt) {
      if (kt < 7) stage(kt + 1, (kt + 1) & 1);
      const int buf = kt & 1;
      short8 af[4], bfr[4];
#pragma unroll
      for (int mi = 0; mi < 4; ++mi)
        af[mi] = *(const short8*)((const char*)&As[buf][0] + wrow * 4096 + mi * 1024 + fragoff);
#pragma unroll
      for (int ni = 0; ni < 4; ++ni)
        bfr[ni] = *(const short8*)((const char*)&Bs[buf][0] + wcol * 4096 + ni * 1024 + fragoff);
#pragma unroll
      for (int mi = 0; mi < 4; ++mi)
#pragma unroll
        for (int ni = 0; ni < 4; ++ni)
          acc[mi][ni] = __builtin_amdgcn_mfma_f32_16x16x32_bf16(af[mi], bfr[ni], acc[mi][ni], 0, 0, 0);
      __syncthreads();
    }

    // epilogue: e = exp(2S); row sums always; col sums for off-diag tiles.
    // C layout: col = lane&15, row = (lane>>4)*4 + reg.
    float rsum[4][4];
    float csum[4] = {0.f, 0.f, 0.f, 0.f};
#pragma unroll
    for (int mi = 0; mi < 4; ++mi)
#pragma unroll
      for (int r = 0; r < 4; ++r) rsum[mi][r] = 0.f;
#pragma unroll
    for (int mi = 0; mi < 4; ++mi)
#pragma unroll
      for (int ni = 0; ni < 4; ++ni)
#pragma unroll
        for (int r = 0; r < 4; ++r) {
          float e = __expf(2.0f * acc[mi][ni][r]);
          rsum[mi][r] += e;
          csum[ni] += e;
        }
#pragma unroll
    for (int m = 1; m < 16; m <<= 1)
#pragma unroll
      for (int mi = 0; mi < 4; ++mi)
#pragma unroll
        for (int r = 0; r < 4; ++r) rsum[mi][r] += __shfl_xor(rsum[mi][r], m);
    if ((lane & 15) == 0) {
      int h = lane >> 4;
#pragma unroll
      for (int mi = 0; mi < 4; ++mi)
#pragma unroll
        for (int r = 0; r < 4; ++r)
          unsafeAtomicAdd(&den[rowbase + wrow * 64 + mi * 16 + h * 4 + r], rsum[mi][r]);
    }
    if (!diag) {
#pragma unroll
      for (int m = 16; m < 64; m <<= 1)
#pragma unroll
        for (int ni = 0; ni < 4; ++ni) csum[ni] += __shfl_xor(csum[ni], m);
      if (lane < 16) {
#pragma unroll
        for (int ni = 0; ni < 4; ++ni)
          unsafeAtomicAdd(&den[colbase + wcol * 64 + ni * 16 + lane], csum[ni]);
      }
    }
  }

  // ---- R8 hierarchical arrive VERBATIM: leaf (<=33/line) then root (64) --
  __syncthreads();
  if (tid == 0) {
    int g = blockIdx.x & 63;
    unsigned tgt = (g < 48) ? 33u : 32u;  // 2096 = 48*33 + 16*32
    unsigned old = __hip_atomic_fetch_add(&leaves[g * 32], 1u, __ATOMIC_RELEASE,
                                          __HIP_MEMORY_SCOPE_AGENT);
    int last = 0;
    if (old == tgt - 1u) {
      unsigned ro = __hip_atomic_fetch_add(root, 1u, __ATOMIC_RELEASE,
                                           __HIP_MEMORY_SCOPE_AGENT);
      last = (ro == 63u) ? 1 : 0;
    }
    shp[0] = last;
  }
  __syncthreads();
  if (!shp[0]) return;
  __builtin_amdgcn_fence(__ATOMIC_ACQUIRE, "agent");  // single buffer_inv

  // ---- tail: log-reduce den; psum from ppos; gsq from partials -----------
  const float e2 = __expf(2.0f);
  float ls = 0.f;
  for (int i = tid; i < TWOB; i += 256) ls += __logf(den[i] - e2);
#pragma unroll
  for (int m = 32; m >= 1; m >>= 1) ls += __shfl_xor(ls, m);
  if (lane == 0) sred[wave] = ls;

  float pp = 0.f;
#pragma unroll
  for (int k = 0; k < 4; ++k) pp += ppos[k * 256 + tid];
#pragma unroll
  for (int m = 32; m >= 1; m >>= 1) pp += __shfl_xor(pp, m);
  if (lane == 0) sred[4 + wave] = pp;

  float gp[4];
#pragma unroll
  for (int g = 0; g < 4; ++g) {
    float v = 0.f;
#pragma unroll
    for (int b = 0; b < 16; ++b) v += vsum_part[(size_t)(b * 4 + g) * 256 + tid];
    gp[g] = v * v;
#pragma unroll
    for (int m = 32; m >= 1; m >>= 1) gp[g] += __shfl_xor(gp[g], m);
  }
  if (lane == 0) {
#pragma unroll
    for (int g = 0; g < 4; ++g) sred[8 + wave * 4 + g] = gp[g];
  }
  __syncthreads();
  if (tid == 0) {
    float lsum = sred[0] + sred[1] + sred[2] + sred[3];
    float psum = sred[4] + sred[5] + sred[6] + sred[7];
    float contrastive = (lsum - 4.0f * psum) / (float)TWOB;
    float fsum = 0.f;
    int uniq = 0;
#pragma unroll
    for (int q = 0; q < 4; ++q) {
      int ci = 0;
#pragma unroll
      for (int b = 0; b < 16; ++b) ci += cnt_part[b * 4 + q];
      float gsq = sred[8 + q] + sred[12 + q] + sred[16 + q] + sred[20 + q];
      float c = (float)ci;
      if (ci > 0) uniq++;
      if (ci > 1) fsum += gsq / (c * (c - 1.0f));
    }
    out[0] = contrastive + 0.1f * (fsum / (uniq > 0 ? (float)uniq : 1.0f));
  }
}

extern "C" void kernel_launch(void* const* d_in, const int* in_sizes, int n_in,
                              void* d_out, int out_size, void* d_ws, size_t ws_size,
                              hipStream_t stream) {
  const float* zi = (const float*)d_in[0];
  const float* zj = (const float*)d_in[1];
  const int* sf = (const int*)d_in[2];
  float* out = (float*)d_out;
  char* ws = (char*)d_ws;
  float* wsf = (float*)ws;                              // den + leaves + root
  unsigned short* znb = (unsigned short*)(ws + 65536);  // 8192x256 bf16 (4MB)
  float* vsum_part = (float*)(ws + 4259840);            // 16x4x256 f32
  int* cnt_part = (int*)(ws + 4276224);                 // 16x4 int
  float* ppos = (float*)(ws + 4276480);                 // 1024 f32

  hipLaunchKernelGGL(norm_kernel, dim3(1024), dim3(256), 0, stream, zi, zj, wsf, ppos, znb);
  hipLaunchKernelGGL(den_kernel, dim3(GRID_B), dim3(256), 0, stream,
                     sf, wsf, znb, vsum_part, cnt_part, ppos, out);
}

// Round 15
// 124.345 us; speedup vs baseline: 4.7785x; 1.1171x over previous
//
#include <hip/hip_runtime.h>
#include <hip/hip_bf16.h>

typedef __attribute__((ext_vector_type(8))) short short8;
typedef __attribute__((ext_vector_type(4))) float f32x4;
typedef __attribute__((address_space(1))) const void gvoid_t;
typedef __attribute__((address_space(3))) void lvoid_t;

#define NB 4096   // B
#define DD 256    // D
#define TWOB 8192
#define NTILES 2080u   // 64*65/2 symmetric 128x128 tiles
#define GSUM_BLOCKS 16

__device__ __forceinline__ unsigned short f2bf(float f) {
  unsigned int u = __float_as_uint(f);
  u += 0x7fffu + ((u >> 16) & 1u);
  return (unsigned short)(u >> 16);
}
__device__ __forceinline__ float bf2f(unsigned short s) {
  return __uint_as_float(((unsigned int)s) << 16);
}

// ws layout (bytes):
//   [0, 32768)          den[8192] f32 (zeroed by norm blocks 0..31)
//   [65536, 4259840)    znb 8192x256 bf16
//   [4259840, 4276224)  vsum_part[16][4][256] f32 (plain stores)
//   [4276224, 4276480)  cnt_part[16][4] int (plain stores)
//   [4276480, 4280576)  ppos[1024] f32 (plain stores)
//
// R14 post-mortem: in-kernel arrive+tail == one dispatch boundary (~23us);
// dispatch-count tricks are a wash. The remaining lever is den itself:
// R1's 2D (64,64) den sustains 2.9 blocks/CU; every 1D variant sustains
// only 1.9 with IDENTICAL resources and inner code. R15 = R11 verbatim
// except den launches as 2D (64,33) with identical linear decode -- a
// single-variable test of the grid-shape/dispatch hypothesis. Also removes
// R11's scal-zeroing race via the proven ppos path.

// ---------------- kernel A: zero den; normalize -> znb bf16; ppos ---------
__global__ __launch_bounds__(256) void norm_kernel(const float* __restrict__ zi,
                                                   const float* __restrict__ zj,
                                                   float* __restrict__ wsf,
                                                   float* __restrict__ ppos,
                                                   unsigned short* __restrict__ znb) {
  __shared__ float sred[4];
  if (blockIdx.x < 32) wsf[blockIdx.x * 256 + threadIdx.x] = 0.f;
  const int lane = threadIdx.x & 63, wave = threadIdx.x >> 6;
  const int i = blockIdx.x * 4 + wave;

  float4 a = ((const float4*)(zi + (size_t)i * DD))[lane];
  float4 b = ((const float4*)(zj + (size_t)i * DD))[lane];
  float sa = a.x * a.x + a.y * a.y + a.z * a.z + a.w * a.w;
  float sb = b.x * b.x + b.y * b.y + b.z * b.z + b.w * b.w;
  float sab = a.x * b.x + a.y * b.y + a.z * b.z + a.w * b.w;
#pragma unroll
  for (int m = 32; m >= 1; m >>= 1) {
    sa += __shfl_xor(sa, m);
    sb += __shfl_xor(sb, m);
    sab += __shfl_xor(sab, m);
  }
  float ra = 1.0f / fmaxf(sqrtf(sa), 1e-8f);
  float rb = 1.0f / fmaxf(sqrtf(sb), 1e-8f);
  ushort4 oa, ob;
  oa.x = f2bf(a.x * ra); oa.y = f2bf(a.y * ra); oa.z = f2bf(a.z * ra); oa.w = f2bf(a.w * ra);
  ob.x = f2bf(b.x * rb); ob.y = f2bf(b.y * rb); ob.z = f2bf(b.z * rb); ob.w = f2bf(b.w * rb);
  ((ushort4*)(znb + (size_t)i * DD))[lane] = oa;
  ((ushort4*)(znb + (size_t)(i + NB) * DD))[lane] = ob;

  if (lane == 0) sred[wave] = sab * ra * rb;  // exact fp32 pos (row i)
  __syncthreads();
  if (threadIdx.x == 0)
    ppos[blockIdx.x] = sred[0] + sred[1] + sred[2] + sred[3];
}

// ---------------- kernel B: 2D (64,33); gsum first; tiles; spares exit ----
__global__ __launch_bounds__(256, 3) void den_kernel(const int* __restrict__ sf,
                                                     float* __restrict__ wsf,
                                                     const unsigned short* __restrict__ znb,
                                                     float* __restrict__ vsum_part,
                                                     int* __restrict__ cnt_part) {
  __shared__ __align__(16) unsigned short As[2][4096];  // 2 x 8KB = 32768 LDS
  __shared__ __align__(16) unsigned short Bs[2][4096];

  float* den = wsf;

  const int tid = threadIdx.x;
  const int lane = tid & 63, wave = tid >> 6;
  const unsigned t_lin = blockIdx.y * 64u + blockIdx.x;

  if (t_lin < GSUM_BLOCKS) {
    // ---- gsum: 256 rows, LDS reduce, plain stores (R11 verbatim) --------
    const int b = (int)t_lin;
    const int r0 = b * 256;
    float acc[4][4];
#pragma unroll
    for (int q = 0; q < 4; ++q)
#pragma unroll
      for (int e = 0; e < 4; ++e) acc[q][e] = 0.f;
    int cnt[4] = {0, 0, 0, 0};
    const int rw = r0 + wave * 64;
    for (int k = 0; k < 64; ++k) {
      int row = rw + k;
      int g = sf[row];
      ushort4 v = ((const ushort4*)(znb + (size_t)row * DD))[lane];
      float f0 = bf2f(v.x), f1 = bf2f(v.y), f2 = bf2f(v.z), f3 = bf2f(v.w);
#pragma unroll
      for (int q = 0; q < 4; ++q) {
        bool sel = (g == q);
        acc[q][0] += sel ? f0 : 0.f;
        acc[q][1] += sel ? f1 : 0.f;
        acc[q][2] += sel ? f2 : 0.f;
        acc[q][3] += sel ? f3 : 0.f;
        cnt[q] += sel ? 1 : 0;
      }
    }
    float4* lsd = (float4*)&As[0][0];
    int* lcnt = (int*)&Bs[0][0];
#pragma unroll
    for (int q = 0; q < 4; ++q) {
      float4 t;
      t.x = acc[q][0]; t.y = acc[q][1]; t.z = acc[q][2]; t.w = acc[q][3];
      lsd[(wave * 4 + q) * 64 + lane] = t;
    }
    if (lane == 0) {
#pragma unroll
      for (int q = 0; q < 4; ++q) lcnt[wave * 4 + q] = cnt[q];
    }
    __syncthreads();
    {
      int g = tid >> 6, l = tid & 63;
      float4 s0 = lsd[(0 + g) * 64 + l];
      float4 s1 = lsd[(4 + g) * 64 + l];
      float4 s2 = lsd[(8 + g) * 64 + l];
      float4 s3 = lsd[(12 + g) * 64 + l];
      float4 s;
      s.x = s0.x + s1.x + s2.x + s3.x;
      s.y = s0.y + s1.y + s2.y + s3.y;
      s.z = s0.z + s1.z + s2.z + s3.z;
      s.w = s0.w + s1.w + s2.w + s3.w;
      ((float4*)(vsum_part + (size_t)(b * 4 + g) * 256))[l] = s;
      if (tid < 4)
        cnt_part[b * 4 + tid] = lcnt[tid] + lcnt[4 + tid] + lcnt[8 + tid] + lcnt[12 + tid];
    }
    return;
  }
  if (t_lin >= NTILES + GSUM_BLOCKS) return;  // 16 spare blocks

  // ---- one symmetric den tile (R11 verbatim decode + inner loop) --------
  unsigned t = t_lin - GSUM_BLOCKS;
  unsigned tr = 0;
  while (t >= 64u - tr) { t -= 64u - tr; ++tr; }
  unsigned tc = tr + t;
  const bool diag = (tr == tc);
  const size_t rowbase = (size_t)tr * 128, colbase = (size_t)tc * 128;

  const int u = lane >> 3;
  const int cp = (lane & 7) ^ u;
  const int ri = 2 * u + (cp >> 2);
  const int kelem = (cp & 3) * 8;
  const int slot = ((((lane & 1) << 2) | (lane >> 4)) ^ ((lane >> 1) & 7));
  const int fragoff = ((lane & 15) >> 1) * 128 + slot * 16;
  const int wrow = wave & 1, wcol = wave >> 1;

  f32x4 zero = {0.f, 0.f, 0.f, 0.f};
  f32x4 acc[4][4];
#pragma unroll
  for (int i = 0; i < 4; ++i)
#pragma unroll
    for (int j = 0; j < 4; ++j) acc[i][j] = zero;

  auto stage = [&](int kt, int buf) {
#pragma unroll
    for (int j = 0; j < 2; ++j) {
      int is = wave * 2 + j;
      const unsigned short* gpa = znb + (rowbase + is * 16 + ri) * DD + kt * 32 + kelem;
      __builtin_amdgcn_global_load_lds((gvoid_t*)gpa, (lvoid_t*)&As[buf][is * 512], 16, 0, 0);
      const unsigned short* gpb = znb + (colbase + is * 16 + ri) * DD + kt * 32 + kelem;
      __builtin_amdgcn_global_load_lds((gvoid_t*)gpb, (lvoid_t*)&Bs[buf][is * 512], 16, 0, 0);
    }
  };

  stage(0, 0);
  __syncthreads();
#pragma unroll
  for (int kt = 0; kt < 8; ++kt) {
    if (kt < 7) stage(kt + 1, (kt + 1) & 1);
    const int buf = kt & 1;
    short8 af[4], bfr[4];
#pragma unroll
    for (int mi = 0; mi < 4; ++mi)
      af[mi] = *(const short8*)((const char*)&As[buf][0] + wrow * 4096 + mi * 1024 + fragoff);
#pragma unroll
    for (int ni = 0; ni < 4; ++ni)
      bfr[ni] = *(const short8*)((const char*)&Bs[buf][0] + wcol * 4096 + ni * 1024 + fragoff);
#pragma unroll
    for (int mi = 0; mi < 4; ++mi)
#pragma unroll
      for (int ni = 0; ni < 4; ++ni)
        acc[mi][ni] = __builtin_amdgcn_mfma_f32_16x16x32_bf16(af[mi], bfr[ni], acc[mi][ni], 0, 0, 0);
    __syncthreads();
  }

  // epilogue: e = exp(2S); row sums always; col sums for off-diag tiles.
  // C layout: col = lane&15, row = (lane>>4)*4 + reg. Block ends right
  // after the atomics (drain after s_endpgm -- R1/R10 behavior).
  float rsum[4][4];
  float csum[4] = {0.f, 0.f, 0.f, 0.f};
#pragma unroll
  for (int mi = 0; mi < 4; ++mi)
#pragma unroll
    for (int r = 0; r < 4; ++r) rsum[mi][r] = 0.f;
#pragma unroll
  for (int mi = 0; mi < 4; ++mi)
#pragma unroll
    for (int ni = 0; ni < 4; ++ni)
#pragma unroll
      for (int r = 0; r < 4; ++r) {
        float e = __expf(2.0f * acc[mi][ni][r]);
        rsum[mi][r] += e;
        csum[ni] += e;
      }
#pragma unroll
  for (int m = 1; m < 16; m <<= 1)
#pragma unroll
    for (int mi = 0; mi < 4; ++mi)
#pragma unroll
      for (int r = 0; r < 4; ++r) rsum[mi][r] += __shfl_xor(rsum[mi][r], m);
  if ((lane & 15) == 0) {
    int h = lane >> 4;
#pragma unroll
    for (int mi = 0; mi < 4; ++mi)
#pragma unroll
      for (int r = 0; r < 4; ++r)
        unsafeAtomicAdd(&den[rowbase + wrow * 64 + mi * 16 + h * 4 + r], rsum[mi][r]);
  }
  if (!diag) {
#pragma unroll
    for (int m = 16; m < 64; m <<= 1)
#pragma unroll
      for (int ni = 0; ni < 4; ++ni) csum[ni] += __shfl_xor(csum[ni], m);
    if (lane < 16) {
#pragma unroll
      for (int ni = 0; ni < 4; ++ni)
        unsafeAtomicAdd(&den[colbase + wcol * 64 + ni * 16 + lane], csum[ni]);
    }
  }
}

// ---------------- kernel C: tail (1 block) --------------------------------
__global__ __launch_bounds__(256) void tail_kernel(const float* __restrict__ wsf,
                                                   const float* __restrict__ vsum_part,
                                                   const int* __restrict__ cnt_part,
                                                   const float* __restrict__ ppos,
                                                   float* __restrict__ out) {
  __shared__ float sred[32];
  const float* den = wsf;
  const int tid = threadIdx.x;
  const int lane = tid & 63, wave = tid >> 6;

  const float e2 = __expf(2.0f);
  float ls = 0.f;
  for (int i = tid; i < TWOB; i += 256) ls += __logf(den[i] - e2);
#pragma unroll
  for (int m = 32; m >= 1; m >>= 1) ls += __shfl_xor(ls, m);
  if (lane == 0) sred[wave] = ls;

  float pp = 0.f;
#pragma unroll
  for (int k = 0; k < 4; ++k) pp += ppos[k * 256 + tid];
#pragma unroll
  for (int m = 32; m >= 1; m >>= 1) pp += __shfl_xor(pp, m);
  if (lane == 0) sred[4 + wave] = pp;

  float gp[4];
#pragma unroll
  for (int g = 0; g < 4; ++g) {
    float v = 0.f;
#pragma unroll
    for (int b = 0; b < 16; ++b) v += vsum_part[(size_t)(b * 4 + g) * 256 + tid];
    gp[g] = v * v;
#pragma unroll
    for (int m = 32; m >= 1; m >>= 1) gp[g] += __shfl_xor(gp[g], m);
  }
  if (lane == 0) {
#pragma unroll
    for (int g = 0; g < 4; ++g) sred[8 + wave * 4 + g] = gp[g];
  }
  __syncthreads();
  if (tid == 0) {
    float lsum = sred[0] + sred[1] + sred[2] + sred[3];
    float psum = sred[4] + sred[5] + sred[6] + sred[7];
    float contrastive = (lsum - 4.0f * psum) / (float)TWOB;
    float fsum = 0.f;
    int uniq = 0;
#pragma unroll
    for (int q = 0; q < 4; ++q) {
      int ci = 0;
#pragma unroll
      for (int b = 0; b < 16; ++b) ci += cnt_part[b * 4 + q];
      float gsq = sred[8 + q] + sred[12 + q] + sred[16 + q] + sred[20 + q];
      float c = (float)ci;
      if (ci > 0) uniq++;
      if (ci > 1) fsum += gsq / (c * (c - 1.0f));
    }
    out[0] = contrastive + 0.1f * (fsum / (uniq > 0 ? (float)uniq : 1.0f));
  }
}

extern "C" void kernel_launch(void* const* d_in, const int* in_sizes, int n_in,
                              void* d_out, int out_size, void* d_ws, size_t ws_size,
                              hipStream_t stream) {
  const float* zi = (const float*)d_in[0];
  const float* zj = (const float*)d_in[1];
  const int* sf = (const int*)d_in[2];
  float* out = (float*)d_out;
  char* ws = (char*)d_ws;
  float* wsf = (float*)ws;                              // den
  unsigned short* znb = (unsigned short*)(ws + 65536);  // 8192x256 bf16 (4MB)
  float* vsum_part = (float*)(ws + 4259840);            // 16x4x256 f32
  int* cnt_part = (int*)(ws + 4276224);                 // 16x4 int
  float* ppos = (float*)(ws + 4276480);                 // 1024 f32

  hipLaunchKernelGGL(norm_kernel, dim3(1024), dim3(256), 0, stream, zi, zj, wsf, ppos, znb);
  hipLaunchKernelGGL(den_kernel, dim3(64, 33), dim3(256), 0, stream,
                     sf, wsf, znb, vsum_part, cnt_part);
  hipLaunchKernelGGL(tail_kernel, dim3(1), dim3(256), 0, stream,
                     wsf, vsum_part, cnt_part, ppos, out);
}

// Round 17
// 108.923 us; speedup vs baseline: 5.4550x; 1.1416x over previous
//
#include <hip/hip_runtime.h>
#include <hip/hip_bf16.h>

typedef __attribute__((ext_vector_type(8))) short short8;
typedef __attribute__((ext_vector_type(4))) float f32x4;
typedef __attribute__((address_space(1))) const void gvoid_t;
typedef __attribute__((address_space(3))) void lvoid_t;

#define NB 4096   // B
#define DD 256    // D
#define TWOB 8192
#define NMACRO 1056u   // sum_{tr} (32 - tr/2) macro 128x256 tiles
#define GSUM_BLOCKS 16

__device__ __forceinline__ unsigned short f2bf(float f) {
  unsigned int u = __float_as_uint(f);
  u += 0x7fffu + ((u >> 16) & 1u);
  return (unsigned short)(u >> 16);
}
__device__ __forceinline__ float bf2f(unsigned short s) {
  return __uint_as_float(((unsigned int)s) << 16);
}

// ws layout (bytes):
//   [0, 32768)          den[8192] f32 (zeroed by norm blocks 0..31)
//   [65536, 4259840)    znb 8192x256 bf16
//   [4259840, 4276224)  vsum_part[16][4][256] f32
//   [4276224, 4276480)  cnt_part[16][4] int
//   [4276480, 4280576)  ppos[1024] f32
//
// R16 post-mortem: macro-tile math was correct; the column writeback used
// `else if (tid < 384)` in a 256-thread block, so cols 128..255 of every
// macro were never added to den (absmax 0.5). R17 fixes ONLY that: all 256
// threads handle one column each; threads 0..127 also handle one row.

// ---------------- kernel A: zero den; normalize -> znb bf16; ppos ---------
__global__ __launch_bounds__(256) void norm_kernel(const float* __restrict__ zi,
                                                   const float* __restrict__ zj,
                                                   float* __restrict__ wsf,
                                                   float* __restrict__ ppos,
                                                   unsigned short* __restrict__ znb) {
  __shared__ float sred[4];
  if (blockIdx.x < 32) wsf[blockIdx.x * 256 + threadIdx.x] = 0.f;
  const int lane = threadIdx.x & 63, wave = threadIdx.x >> 6;
  const int i = blockIdx.x * 4 + wave;

  float4 a = ((const float4*)(zi + (size_t)i * DD))[lane];
  float4 b = ((const float4*)(zj + (size_t)i * DD))[lane];
  float sa = a.x * a.x + a.y * a.y + a.z * a.z + a.w * a.w;
  float sb = b.x * b.x + b.y * b.y + b.z * b.z + b.w * b.w;
  float sab = a.x * b.x + a.y * b.y + a.z * b.z + a.w * b.w;
#pragma unroll
  for (int m = 32; m >= 1; m >>= 1) {
    sa += __shfl_xor(sa, m);
    sb += __shfl_xor(sb, m);
    sab += __shfl_xor(sab, m);
  }
  float ra = 1.0f / fmaxf(sqrtf(sa), 1e-8f);
  float rb = 1.0f / fmaxf(sqrtf(sb), 1e-8f);
  ushort4 oa, ob;
  oa.x = f2bf(a.x * ra); oa.y = f2bf(a.y * ra); oa.z = f2bf(a.z * ra); oa.w = f2bf(a.w * ra);
  ob.x = f2bf(b.x * rb); ob.y = f2bf(b.y * rb); ob.z = f2bf(b.z * rb); ob.w = f2bf(b.w * rb);
  ((ushort4*)(znb + (size_t)i * DD))[lane] = oa;
  ((ushort4*)(znb + (size_t)(i + NB) * DD))[lane] = ob;

  if (lane == 0) sred[wave] = sab * ra * rb;  // exact fp32 pos (row i)
  __syncthreads();
  if (threadIdx.x == 0)
    ppos[blockIdx.x] = sred[0] + sred[1] + sred[2] + sred[3];
}

// ---------------- kernel B: gsum + 128x256 macro den tiles ----------------
__global__ __launch_bounds__(256, 2) void den_kernel(const int* __restrict__ sf,
                                                     float* __restrict__ wsf,
                                                     const unsigned short* __restrict__ znb,
                                                     float* __restrict__ vsum_part,
                                                     int* __restrict__ cnt_part) {
  __shared__ __align__(16) unsigned short As[2][4096];  // 16 KB (A: 128 rows)
  __shared__ __align__(16) unsigned short Bs[2][8192];  // 32 KB (B: 256 cols)

  float* den = wsf;

  const int tid = threadIdx.x;
  const int lane = tid & 63, wave = tid >> 6;
  const unsigned t_lin = blockIdx.y * 64u + blockIdx.x;

  if (t_lin < GSUM_BLOCKS) {
    // ---- gsum: 256 rows, LDS reduce, plain stores (R11/R15 verbatim) ----
    const int b = (int)t_lin;
    const int r0 = b * 256;
    float acc[4][4];
#pragma unroll
    for (int q = 0; q < 4; ++q)
#pragma unroll
      for (int e = 0; e < 4; ++e) acc[q][e] = 0.f;
    int cnt[4] = {0, 0, 0, 0};
    const int rw = r0 + wave * 64;
    for (int k = 0; k < 64; ++k) {
      int row = rw + k;
      int g = sf[row];
      ushort4 v = ((const ushort4*)(znb + (size_t)row * DD))[lane];
      float f0 = bf2f(v.x), f1 = bf2f(v.y), f2 = bf2f(v.z), f3 = bf2f(v.w);
#pragma unroll
      for (int q = 0; q < 4; ++q) {
        bool sel = (g == q);
        acc[q][0] += sel ? f0 : 0.f;
        acc[q][1] += sel ? f1 : 0.f;
        acc[q][2] += sel ? f2 : 0.f;
        acc[q][3] += sel ? f3 : 0.f;
        cnt[q] += sel ? 1 : 0;
      }
    }
    float4* lsd = (float4*)&As[0][0];
    int* lcnt = (int*)&Bs[0][0];
#pragma unroll
    for (int q = 0; q < 4; ++q) {
      float4 t;
      t.x = acc[q][0]; t.y = acc[q][1]; t.z = acc[q][2]; t.w = acc[q][3];
      lsd[(wave * 4 + q) * 64 + lane] = t;
    }
    if (lane == 0) {
#pragma unroll
      for (int q = 0; q < 4; ++q) lcnt[wave * 4 + q] = cnt[q];
    }
    __syncthreads();
    {
      int g = tid >> 6, l = tid & 63;
      float4 s0 = lsd[(0 + g) * 64 + l];
      float4 s1 = lsd[(4 + g) * 64 + l];
      float4 s2 = lsd[(8 + g) * 64 + l];
      float4 s3 = lsd[(12 + g) * 64 + l];
      float4 s;
      s.x = s0.x + s1.x + s2.x + s3.x;
      s.y = s0.y + s1.y + s2.y + s3.y;
      s.z = s0.z + s1.z + s2.z + s3.z;
      s.w = s0.w + s1.w + s2.w + s3.w;
      ((float4*)(vsum_part + (size_t)(b * 4 + g) * 256))[l] = s;
      if (tid < 4)
        cnt_part[b * 4 + tid] = lcnt[tid] + lcnt[4 + tid] + lcnt[8 + tid] + lcnt[12 + tid];
    }
    return;
  }
  if (t_lin >= NMACRO + GSUM_BLOCKS) return;  // spares

  // ---- one 128x256 macro tile ------------------------------------------
  unsigned t = t_lin - GSUM_BLOCKS;
  unsigned tr = 0;
  while (t >= 32u - (tr >> 1)) { t -= 32u - (tr >> 1); ++tr; }
  unsigned c = (tr >> 1) + t;
  const size_t rowbase = (size_t)tr * 128;
  const size_t colbase = (size_t)c * 256;
  const int tc0 = (int)(2 * c), tc1 = (int)(2 * c + 1);

  const int u = lane >> 3;
  const int cp = (lane & 7) ^ u;
  const int ri = 2 * u + (cp >> 2);
  const int kelem = (cp & 3) * 8;
  const int slot = ((((lane & 1) << 2) | (lane >> 4)) ^ ((lane >> 1) & 7));
  const int fragoff = ((lane & 15) >> 1) * 128 + slot * 16;
  const int wrow = wave & 1, wcol = wave >> 1;

  // wave-uniform symmetry flags for this wave's 128-col half
  const int tch = wcol ? tc1 : tc0;
  const float fr = (tch >= (int)tr) ? 1.f : 0.f;  // include in row sums
  const float fc = (tch > (int)tr) ? 1.f : 0.f;   // include in col sums

  f32x4 zero = {0.f, 0.f, 0.f, 0.f};
  f32x4 acc[4][8];
#pragma unroll
  for (int i = 0; i < 4; ++i)
#pragma unroll
    for (int j = 0; j < 8; ++j) acc[i][j] = zero;

  auto stage = [&](int kt, int buf) {
#pragma unroll
    for (int j = 0; j < 2; ++j) {
      int is = wave * 2 + j;
      const unsigned short* gpa = znb + (rowbase + is * 16 + ri) * DD + kt * 32 + kelem;
      __builtin_amdgcn_global_load_lds((gvoid_t*)gpa, (lvoid_t*)&As[buf][is * 512], 16, 0, 0);
    }
#pragma unroll
    for (int j = 0; j < 4; ++j) {
      int is = wave * 4 + j;
      const unsigned short* gpb = znb + (colbase + is * 16 + ri) * DD + kt * 32 + kelem;
      __builtin_amdgcn_global_load_lds((gvoid_t*)gpb, (lvoid_t*)&Bs[buf][is * 512], 16, 0, 0);
    }
  };

  stage(0, 0);
  __syncthreads();
#pragma unroll
  for (int kt = 0; kt < 8; ++kt) {
    if (kt < 7) stage(kt + 1, (kt + 1) & 1);
    const int buf = kt & 1;
    short8 af[4], bfr[8];
#pragma unroll
    for (int mi = 0; mi < 4; ++mi)
      af[mi] = *(const short8*)((const char*)&As[0][0] + buf * 8192 + wrow * 4096 + mi * 1024 + fragoff);
#pragma unroll
    for (int ni = 0; ni < 8; ++ni)
      bfr[ni] = *(const short8*)((const char*)&Bs[0][0] + buf * 16384 + wcol * 8192 + ni * 1024 + fragoff);
#pragma unroll
    for (int mi = 0; mi < 4; ++mi)
#pragma unroll
      for (int ni = 0; ni < 8; ++ni)
        acc[mi][ni] = __builtin_amdgcn_mfma_f32_16x16x32_bf16(af[mi], bfr[ni], acc[mi][ni], 0, 0, 0);
    __syncthreads();
  }

  // epilogue: e = exp(2S); row/col sums with wave-uniform fr/fc; combine in
  // LDS; atomics; end at s_endpgm. C layout: col=lane&15, row=(lane>>4)*4+reg.
  float rsum[4][4];
  float csum[8];
#pragma unroll
  for (int mi = 0; mi < 4; ++mi)
#pragma unroll
    for (int r = 0; r < 4; ++r) rsum[mi][r] = 0.f;
#pragma unroll
  for (int ni = 0; ni < 8; ++ni) csum[ni] = 0.f;
#pragma unroll
  for (int mi = 0; mi < 4; ++mi)
#pragma unroll
    for (int ni = 0; ni < 8; ++ni)
#pragma unroll
      for (int r = 0; r < 4; ++r) {
        float e = __expf(2.0f * acc[mi][ni][r]);
        rsum[mi][r] += e;
        csum[ni] += e;
      }
#pragma unroll
  for (int m = 1; m < 16; m <<= 1)
#pragma unroll
    for (int mi = 0; mi < 4; ++mi)
#pragma unroll
      for (int r = 0; r < 4; ++r) rsum[mi][r] += __shfl_xor(rsum[mi][r], m);
#pragma unroll
  for (int m = 16; m < 64; m <<= 1)
#pragma unroll
    for (int ni = 0; ni < 8; ++ni) csum[ni] += __shfl_xor(csum[ni], m);

  float* Lr = (float*)&As[0][0];  // [2][128] indexed by wcol
  float* Lc = Lr + 256;           // [2][256] indexed by wrow
  if ((lane & 15) == 0) {
    int h = lane >> 4;
#pragma unroll
    for (int mi = 0; mi < 4; ++mi)
#pragma unroll
      for (int r = 0; r < 4; ++r)
        Lr[wcol * 128 + wrow * 64 + mi * 16 + h * 4 + r] = rsum[mi][r] * fr;
  }
  if (lane < 16) {
#pragma unroll
    for (int ni = 0; ni < 8; ++ni)
      Lc[wrow * 256 + wcol * 128 + ni * 16 + lane] = csum[ni] * fc;
  }
  __syncthreads();
  // R17 fix: 256 threads each take one column; threads 0..127 also a row.
  if (tid < 128) {
    unsafeAtomicAdd(&den[rowbase + tid], Lr[tid] + Lr[128 + tid]);
  }
  {
    float v = Lc[tid] + Lc[256 + tid];
    if (v != 0.f) unsafeAtomicAdd(&den[colbase + tid], v);
  }
}

// ---------------- kernel C: tail (1 block) --------------------------------
__global__ __launch_bounds__(256) void tail_kernel(const float* __restrict__ wsf,
                                                   const float* __restrict__ vsum_part,
                                                   const int* __restrict__ cnt_part,
                                                   const float* __restrict__ ppos,
                                                   float* __restrict__ out) {
  __shared__ float sred[32];
  const float* den = wsf;
  const int tid = threadIdx.x;
  const int lane = tid & 63, wave = tid >> 6;

  const float e2 = __expf(2.0f);
  float ls = 0.f;
  for (int i = tid; i < TWOB; i += 256) ls += __logf(den[i] - e2);
#pragma unroll
  for (int m = 32; m >= 1; m >>= 1) ls += __shfl_xor(ls, m);
  if (lane == 0) sred[wave] = ls;

  float pp = 0.f;
#pragma unroll
  for (int k = 0; k < 4; ++k) pp += ppos[k * 256 + tid];
#pragma unroll
  for (int m = 32; m >= 1; m >>= 1) pp += __shfl_xor(pp, m);
  if (lane == 0) sred[4 + wave] = pp;

  float gp[4];
#pragma unroll
  for (int g = 0; g < 4; ++g) {
    float v = 0.f;
#pragma unroll
    for (int b = 0; b < 16; ++b) v += vsum_part[(size_t)(b * 4 + g) * 256 + tid];
    gp[g] = v * v;
#pragma unroll
    for (int m = 32; m >= 1; m >>= 1) gp[g] += __shfl_xor(gp[g], m);
  }
  if (lane == 0) {
#pragma unroll
    for (int g = 0; g < 4; ++g) sred[8 + wave * 4 + g] = gp[g];
  }
  __syncthreads();
  if (tid == 0) {
    float lsum = sred[0] + sred[1] + sred[2] + sred[3];
    float psum = sred[4] + sred[5] + sred[6] + sred[7];
    float contrastive = (lsum - 4.0f * psum) / (float)TWOB;
    float fsum = 0.f;
    int uniq = 0;
#pragma unroll
    for (int q = 0; q < 4; ++q) {
      int ci = 0;
#pragma unroll
      for (int b = 0; b < 16; ++b) ci += cnt_part[b * 4 + q];
      float gsq = sred[8 + q] + sred[12 + q] + sred[16 + q] + sred[20 + q];
      float c = (float)ci;
      if (ci > 0) uniq++;
      if (ci > 1) fsum += gsq / (c * (c - 1.0f));
    }
    out[0] = contrastive + 0.1f * (fsum / (uniq > 0 ? (float)uniq : 1.0f));
  }
}

extern "C" void kernel_launch(void* const* d_in, const int* in_sizes, int n_in,
                              void* d_out, int out_size, void* d_ws, size_t ws_size,
                              hipStream_t stream) {
  const float* zi = (const float*)d_in[0];
  const float* zj = (const float*)d_in[1];
  const int* sf = (const int*)d_in[2];
  float* out = (float*)d_out;
  char* ws = (char*)d_ws;
  float* wsf = (float*)ws;                              // den
  unsigned short* znb = (unsigned short*)(ws + 65536);  // 8192x256 bf16 (4MB)
  float* vsum_part = (float*)(ws + 4259840);            // 16x4x256 f32
  int* cnt_part = (int*)(ws + 4276224);                 // 16x4 int
  float* ppos = (float*)(ws + 4276480);                 // 1024 f32

  hipLaunchKernelGGL(norm_kernel, dim3(1024), dim3(256), 0, stream, zi, zj, wsf, ppos, znb);
  hipLaunchKernelGGL(den_kernel, dim3(64, 17), dim3(256), 0, stream,
                     sf, wsf, znb, vsum_part, cnt_part);
  hipLaunchKernelGGL(tail_kernel, dim3(1), dim3(256), 0, stream,
                     wsf, vsum_part, cnt_part, ppos, out);
}